// Round 3
// baseline (61.377 us; speedup 1.0000x reference)
//
#include <hip/hip_runtime.h>

#define CELL_F 50            // floats per cell: 2 boxes x (1 conf + 20 cls + 4 xywh)
#define LAMBDA_COORD 5.0f
#define LAMBDA_NOOBJ 0.5f
#define BLOCK 256

__device__ __forceinline__ float iou8(float ax, float ay, float aw, float ah,
                                      float bx, float by, float bw, float bh) {
    float w = fminf(ax + aw * 0.5f, bx + bw * 0.5f) - fmaxf(ax - aw * 0.5f, bx - bw * 0.5f);
    float h = fminf(ay + ah * 0.5f, by + bh * 0.5f) - fmaxf(ay - ah * 0.5f, by - bh * 0.5f);
    float cross = w * h;
    float denom = aw * ah + bw * bh - cross;
    float iou = cross / denom;
    return (w <= 0.0f || h <= 0.0f) ? 0.0f : iou;
}

__global__ __launch_bounds__(BLOCK) void yolo_loss_partial(
        const float* __restrict__ pr, const float* __restrict__ gt,
        float* __restrict__ partial, int ncells) {
    int cell = blockIdx.x * BLOCK + threadIdx.x;
    float acc = 0.0f;
    if (cell < ncells) {
        const float* p = pr + (size_t)cell * CELL_F;
        const float* g = gt + (size_t)cell * CELL_F;
        float P[CELL_F], G[CELL_F];
        #pragma unroll
        for (int i = 0; i < CELL_F / 2; ++i) {
            float2 v = *reinterpret_cast<const float2*>(p + 2 * i);
            P[2 * i] = v.x; P[2 * i + 1] = v.y;
            float2 u = *reinterpret_cast<const float2*>(g + 2 * i);
            G[2 * i] = u.x; G[2 * i + 1] = u.y;
        }

        float gc0 = G[0], gc1 = G[25];
        int obj_num = (gc0 != 0.0f ? 1 : 0) + (gc1 != 0.0f ? 1 : 0);
        float pc0 = P[0], pc1 = P[25];

        if (obj_num == 0) {
            acc = LAMBDA_NOOBJ * (pc0 + pc1);
        } else {
            float c0 = pc0 - 1.0f, c1 = pc1 - 1.0f;
            acc = c0 * c0 + c1 * c1;

            // IoU of each predictor box vs each gt box
            float iou00 = iou8(P[21], P[22], P[23], P[24], G[21], G[22], G[23], G[24]);
            float iou01 = iou8(P[21], P[22], P[23], P[24], G[46], G[47], G[48], G[49]);
            float iou10 = iou8(P[46], P[47], P[48], P[49], G[21], G[22], G[23], G[24]);
            float iou11 = iou8(P[46], P[47], P[48], P[49], G[46], G[47], G[48], G[49]);

            // valid[j] = j < obj_num; j=0 always valid here (obj_num >= 1)
            bool v1 = (obj_num > 1);
            float m01 = v1 ? iou01 : -1.0f;
            float m11 = v1 ? iou11 : -1.0f;
            // first-max argmax: index 1 only if strictly greater
            int rsp0 = (m01 > iou00) ? 1 : 0;
            int rsp1 = (m11 > iou10) ? 1 : 0;

            // class MSE for all 4 predictor/gt combos, pick with rsp
            float s00 = 0.0f, s01 = 0.0f, s10 = 0.0f, s11 = 0.0f;
            #pragma unroll
            for (int k = 0; k < 20; ++k) {
                float pk0 = P[1 + k], pk1 = P[26 + k];
                float gk0 = G[1 + k], gk1 = G[26 + k];
                float d;
                d = pk0 - gk0; s00 += d * d;
                d = pk0 - gk1; s01 += d * d;
                d = pk1 - gk0; s10 += d * d;
                d = pk1 - gk1; s11 += d * d;
            }
            float cls0 = (rsp0 ? s01 : s00) * (1.0f / 20.0f);
            float cls1 = (rsp1 ? s11 : s10) * (1.0f / 20.0f);

            // coord loss, predictor 0
            {
                float rx = rsp0 ? G[46] : G[21];
                float ry = rsp0 ? G[47] : G[22];
                float rw = rsp0 ? G[48] : G[23];
                float rh = rsp0 ? G[49] : G[24];
                float dx = P[21] - rx, dy = P[22] - ry;
                float dw = sqrtf(P[23]) - sqrtf(rw);
                float dh = sqrtf(P[24]) - sqrtf(rh);
                acc += LAMBDA_COORD * (dx * dx + dy * dy + dw * dw + dh * dh) + cls0;
            }
            // coord loss, predictor 1
            {
                float rx = rsp1 ? G[46] : G[21];
                float ry = rsp1 ? G[47] : G[22];
                float rw = rsp1 ? G[48] : G[23];
                float rh = rsp1 ? G[49] : G[24];
                float dx = P[46] - rx, dy = P[47] - ry;
                float dw = sqrtf(P[48]) - sqrtf(rw);
                float dh = sqrtf(P[49]) - sqrtf(rh);
                acc += LAMBDA_COORD * (dx * dx + dy * dy + dw * dw + dh * dh) + cls1;
            }
        }
    }

    // block reduction: wave shfl tree, then LDS across the 4 waves
    #pragma unroll
    for (int off = 32; off > 0; off >>= 1) acc += __shfl_down(acc, off);
    __shared__ float wsum[BLOCK / 64];
    int lane = threadIdx.x & 63;
    int wid = threadIdx.x >> 6;
    if (lane == 0) wsum[wid] = acc;
    __syncthreads();
    if (threadIdx.x == 0) {
        float s = wsum[0] + wsum[1] + wsum[2] + wsum[3];
        partial[blockIdx.x] = s;
    }
}

__global__ __launch_bounds__(BLOCK) void yolo_loss_final(
        const float* __restrict__ partial, int n, float* __restrict__ out,
        float inv_batch) {
    float acc = 0.0f;
    for (int i = threadIdx.x; i < n; i += BLOCK) acc += partial[i];
    #pragma unroll
    for (int off = 32; off > 0; off >>= 1) acc += __shfl_down(acc, off);
    __shared__ float wsum[BLOCK / 64];
    int lane = threadIdx.x & 63;
    int wid = threadIdx.x >> 6;
    if (lane == 0) wsum[wid] = acc;
    __syncthreads();
    if (threadIdx.x == 0) {
        out[0] = (wsum[0] + wsum[1] + wsum[2] + wsum[3]) * inv_batch;
    }
}

extern "C" void kernel_launch(void* const* d_in, const int* in_sizes, int n_in,
                              void* d_out, int out_size, void* d_ws, size_t ws_size,
                              hipStream_t stream) {
    const float* pr = (const float*)d_in[0];
    const float* gt = (const float*)d_in[1];
    float* out = (float*)d_out;
    float* partial = (float*)d_ws;

    int total_elems = in_sizes[0];
    int ncells = total_elems / CELL_F;          // 401408
    int batch = total_elems / 2450;             // 8192
    int blocks = (ncells + BLOCK - 1) / BLOCK;  // 1568

    yolo_loss_partial<<<blocks, BLOCK, 0, stream>>>(pr, gt, partial, ncells);
    yolo_loss_final<<<1, BLOCK, 0, stream>>>(partial, blocks, out, 1.0f / (float)batch);
}

// Round 4
// 41.472 us; speedup vs baseline: 1.4800x; 1.4800x over previous
//
#include <hip/hip_runtime.h>

#define CELL_F 50            // floats per cell: 2 boxes x (1 conf + 20 cls + 4 xywh)
#define LAMBDA_COORD 5.0f
#define LAMBDA_NOOBJ 0.5f
#define BLOCK 256
#define CPB 256                       // cells per block
#define TILE_F (CPB * CELL_F)         // 12800 floats
#define TILE_V4 (TILE_F / 4)          // 3200 float4 = 51200 B LDS

__device__ __forceinline__ float iou8(float ax, float ay, float aw, float ah,
                                      float bx, float by, float bw, float bh) {
    float w = fminf(ax + aw * 0.5f, bx + bw * 0.5f) - fmaxf(ax - aw * 0.5f, bx - bw * 0.5f);
    float h = fminf(ay + ah * 0.5f, by + bh * 0.5f) - fmaxf(ay - ah * 0.5f, by - bh * 0.5f);
    float cross = w * h;
    float denom = aw * ah + bw * bh - cross;
    float iou = cross / denom;
    return (w <= 0.0f || h <= 0.0f) ? 0.0f : iou;
}

__global__ __launch_bounds__(BLOCK) void yolo_loss_partial(
        const float4* __restrict__ pr4, const float4* __restrict__ gt4,
        float* __restrict__ partial, int ncells, int total_v4) {
    __shared__ float4 tile4[TILE_V4];
    float* tile = reinterpret_cast<float*>(tile4);
    const int tid = threadIdx.x;
    const size_t base_v4 = (size_t)blockIdx.x * TILE_V4;
    const int cell = blockIdx.x * CPB + tid;

    // ---- stage pr tile: fully coalesced float4 loads ----
    #pragma unroll
    for (int i = 0; i < TILE_V4 / BLOCK; ++i) {          // 12 full rounds
        int idx = i * BLOCK + tid;
        size_t gi = base_v4 + idx;
        tile4[idx] = (gi < (size_t)total_v4) ? pr4[gi] : make_float4(0.f, 0.f, 0.f, 0.f);
    }
    {   // remaining 128 float4
        int idx = (TILE_V4 / BLOCK) * BLOCK + tid;
        if (idx < TILE_V4) {
            size_t gi = base_v4 + idx;
            tile4[idx] = (gi < (size_t)total_v4) ? pr4[gi] : make_float4(0.f, 0.f, 0.f, 0.f);
        }
    }
    __syncthreads();

    float P[CELL_F];
    {
        const float* src = tile + tid * CELL_F;          // 8B-aligned (200B stride)
        #pragma unroll
        for (int i = 0; i < CELL_F / 2; ++i) {
            float2 v = *reinterpret_cast<const float2*>(src + 2 * i);
            P[2 * i] = v.x; P[2 * i + 1] = v.y;
        }
    }
    __syncthreads();

    // ---- stage gt tile into the same buffer ----
    #pragma unroll
    for (int i = 0; i < TILE_V4 / BLOCK; ++i) {
        int idx = i * BLOCK + tid;
        size_t gi = base_v4 + idx;
        tile4[idx] = (gi < (size_t)total_v4) ? gt4[gi] : make_float4(0.f, 0.f, 0.f, 0.f);
    }
    {
        int idx = (TILE_V4 / BLOCK) * BLOCK + tid;
        if (idx < TILE_V4) {
            size_t gi = base_v4 + idx;
            tile4[idx] = (gi < (size_t)total_v4) ? gt4[gi] : make_float4(0.f, 0.f, 0.f, 0.f);
        }
    }
    __syncthreads();

    float G[CELL_F];
    {
        const float* src = tile + tid * CELL_F;
        #pragma unroll
        for (int i = 0; i < CELL_F / 2; ++i) {
            float2 v = *reinterpret_cast<const float2*>(src + 2 * i);
            G[2 * i] = v.x; G[2 * i + 1] = v.y;
        }
    }

    float acc = 0.0f;
    if (cell < ncells) {
        float gc0 = G[0], gc1 = G[25];
        int obj_num = (gc0 != 0.0f ? 1 : 0) + (gc1 != 0.0f ? 1 : 0);
        float pc0 = P[0], pc1 = P[25];

        if (obj_num == 0) {
            acc = LAMBDA_NOOBJ * (pc0 + pc1);
        } else {
            float c0 = pc0 - 1.0f, c1 = pc1 - 1.0f;
            acc = c0 * c0 + c1 * c1;

            float iou00 = iou8(P[21], P[22], P[23], P[24], G[21], G[22], G[23], G[24]);
            float iou01 = iou8(P[21], P[22], P[23], P[24], G[46], G[47], G[48], G[49]);
            float iou10 = iou8(P[46], P[47], P[48], P[49], G[21], G[22], G[23], G[24]);
            float iou11 = iou8(P[46], P[47], P[48], P[49], G[46], G[47], G[48], G[49]);

            bool v1 = (obj_num > 1);
            float m01 = v1 ? iou01 : -1.0f;
            float m11 = v1 ? iou11 : -1.0f;
            int rsp0 = (m01 > iou00) ? 1 : 0;   // first-max argmax
            int rsp1 = (m11 > iou10) ? 1 : 0;

            float s00 = 0.0f, s01 = 0.0f, s10 = 0.0f, s11 = 0.0f;
            #pragma unroll
            for (int k = 0; k < 20; ++k) {
                float pk0 = P[1 + k], pk1 = P[26 + k];
                float gk0 = G[1 + k], gk1 = G[26 + k];
                float d;
                d = pk0 - gk0; s00 += d * d;
                d = pk0 - gk1; s01 += d * d;
                d = pk1 - gk0; s10 += d * d;
                d = pk1 - gk1; s11 += d * d;
            }
            float cls0 = (rsp0 ? s01 : s00) * (1.0f / 20.0f);
            float cls1 = (rsp1 ? s11 : s10) * (1.0f / 20.0f);

            {
                float rx = rsp0 ? G[46] : G[21];
                float ry = rsp0 ? G[47] : G[22];
                float rw = rsp0 ? G[48] : G[23];
                float rh = rsp0 ? G[49] : G[24];
                float dx = P[21] - rx, dy = P[22] - ry;
                float dw = sqrtf(P[23]) - sqrtf(rw);
                float dh = sqrtf(P[24]) - sqrtf(rh);
                acc += LAMBDA_COORD * (dx * dx + dy * dy + dw * dw + dh * dh) + cls0;
            }
            {
                float rx = rsp1 ? G[46] : G[21];
                float ry = rsp1 ? G[47] : G[22];
                float rw = rsp1 ? G[48] : G[23];
                float rh = rsp1 ? G[49] : G[24];
                float dx = P[46] - rx, dy = P[47] - ry;
                float dw = sqrtf(P[48]) - sqrtf(rw);
                float dh = sqrtf(P[49]) - sqrtf(rh);
                acc += LAMBDA_COORD * (dx * dx + dy * dy + dw * dw + dh * dh) + cls1;
            }
        }
    }

    // block reduction: wave shfl tree, then LDS across the 4 waves
    #pragma unroll
    for (int off = 32; off > 0; off >>= 1) acc += __shfl_down(acc, off);
    __shared__ float wsum[BLOCK / 64];
    int lane = threadIdx.x & 63;
    int wid = threadIdx.x >> 6;
    if (lane == 0) wsum[wid] = acc;
    __syncthreads();
    if (threadIdx.x == 0) {
        partial[blockIdx.x] = wsum[0] + wsum[1] + wsum[2] + wsum[3];
    }
}

__global__ __launch_bounds__(BLOCK) void yolo_loss_final(
        const float* __restrict__ partial, int n, float* __restrict__ out,
        float inv_batch) {
    float acc = 0.0f;
    for (int i = threadIdx.x; i < n; i += BLOCK) acc += partial[i];
    #pragma unroll
    for (int off = 32; off > 0; off >>= 1) acc += __shfl_down(acc, off);
    __shared__ float wsum[BLOCK / 64];
    int lane = threadIdx.x & 63;
    int wid = threadIdx.x >> 6;
    if (lane == 0) wsum[wid] = acc;
    __syncthreads();
    if (threadIdx.x == 0) {
        out[0] = (wsum[0] + wsum[1] + wsum[2] + wsum[3]) * inv_batch;
    }
}

extern "C" void kernel_launch(void* const* d_in, const int* in_sizes, int n_in,
                              void* d_out, int out_size, void* d_ws, size_t ws_size,
                              hipStream_t stream) {
    const float4* pr4 = (const float4*)d_in[0];
    const float4* gt4 = (const float4*)d_in[1];
    float* out = (float*)d_out;
    float* partial = (float*)d_ws;

    int total_elems = in_sizes[0];            // 20,070,400
    int ncells = total_elems / CELL_F;        // 401,408
    int batch = total_elems / 2450;           // 8192
    int total_v4 = total_elems / 4;           // 5,017,600 (divisible)
    int blocks = (ncells + CPB - 1) / CPB;    // 1568

    yolo_loss_partial<<<blocks, BLOCK, 0, stream>>>(pr4, gt4, partial, ncells, total_v4);
    yolo_loss_final<<<1, BLOCK, 0, stream>>>(partial, blocks, out, 1.0f / (float)batch);
}